// Round 4
// baseline (4430.162 us; speedup 1.0000x reference)
//
#include <hip/hip_runtime.h>
#include <math.h>

#define NPROD 704
#define FS 136  // flag-row stride (ints) per batch

// global -> LDS async copy (sizes must be literal)
#define GLL16(gp, lp_)                                                     \
  __builtin_amdgcn_global_load_lds(                                        \
      (const __attribute__((address_space(1))) void*)(gp),                 \
      (__attribute__((address_space(3))) void*)(lp_), 16, 0, 0)
#define GLL4(gp, lp_)                                                      \
  __builtin_amdgcn_global_load_lds(                                        \
      (const __attribute__((address_space(1))) void*)(gp),                 \
      (__attribute__((address_space(3))) void*)(lp_), 4, 0, 0)

__device__ inline float wave_max64(float v) {
#pragma unroll
  for (int off = 32; off > 0; off >>= 1) v = fmaxf(v, __shfl_xor(v, off, 64));
  return v;
}
__device__ inline float wave_sum64(float v) {
#pragma unroll
  for (int off = 32; off > 0; off >>= 1) v += __shfl_xor(v, off, 64);
  return v;
}

// wave64 max via DPP (row_shr 1/2/4/8 + row_bcast15/31), result broadcast
__device__ inline float wave_max_dpp(float x) {
  int xi = __float_as_int(x);
  x = fmaxf(x, __int_as_float(__builtin_amdgcn_update_dpp(xi, xi, 0x111, 0xf, 0xf, false)));
  xi = __float_as_int(x);
  x = fmaxf(x, __int_as_float(__builtin_amdgcn_update_dpp(xi, xi, 0x112, 0xf, 0xf, false)));
  xi = __float_as_int(x);
  x = fmaxf(x, __int_as_float(__builtin_amdgcn_update_dpp(xi, xi, 0x114, 0xf, 0xf, false)));
  xi = __float_as_int(x);
  x = fmaxf(x, __int_as_float(__builtin_amdgcn_update_dpp(xi, xi, 0x118, 0xf, 0xf, false)));
  xi = __float_as_int(x);
  x = fmaxf(x, __int_as_float(__builtin_amdgcn_update_dpp(xi, xi, 0x142, 0xa, 0xf, false)));
  xi = __float_as_int(x);
  x = fmaxf(x, __int_as_float(__builtin_amdgcn_update_dpp(xi, xi, 0x143, 0xc, 0xf, false)));
  return __int_as_float(__builtin_amdgcn_readlane(__float_as_int(x), 63));
}

__global__ void k0_init(int* __restrict__ flags, int n) {
  for (int i = threadIdx.x; i < n; i += blockDim.x) flags[i] = 0;
}

// LDS layout (floats): P ring 3*16*256 = 12288 | Q ring 3*64 = 192 | fin 513
__global__ __launch_bounds__(256, 1) void mega(
    const float* __restrict__ lp, const int* __restrict__ targets,
    const int* __restrict__ in_len, const int* __restrict__ tgt_len,
    float* __restrict__ gw, float* __restrict__ qw, int* __restrict__ flags,
    float* __restrict__ tot, int T, int S, int Tp) {
  __shared__ float lds[13056];
  const int lane = threadIdx.x & 63;

  if (blockIdx.x >= 64) {
    // ---------------- producer: log-softmax + gather, t-major ----------------
    const int wid = (blockIdx.x - 64) * 4 + (threadIdx.x >> 6);
    float* rowbuf = lds + (threadIdx.x >> 6) * 1024;
    const int nw = NPROD * 4;
    const int total = T * 64;
    for (int rowid = wid; rowid < total; rowid += nw) {
      const int t = rowid >> 6;
      const int b = rowid & 63;
      const float* row = lp + ((size_t)b * T + t) * 1024;
      const float4 v0 = *(const float4*)(row + 0 * 256 + 4 * lane);
      const float4 v1 = *(const float4*)(row + 1 * 256 + 4 * lane);
      const float4 v2 = *(const float4*)(row + 2 * 256 + 4 * lane);
      const float4 v3 = *(const float4*)(row + 3 * 256 + 4 * lane);
      float mx = fmaxf(fmaxf(v0.x, v0.y), fmaxf(v0.z, v0.w));
      mx = fmaxf(mx, fmaxf(fmaxf(v1.x, v1.y), fmaxf(v1.z, v1.w)));
      mx = fmaxf(mx, fmaxf(fmaxf(v2.x, v2.y), fmaxf(v2.z, v2.w)));
      mx = fmaxf(mx, fmaxf(fmaxf(v3.x, v3.y), fmaxf(v3.z, v3.w)));
      mx = wave_max64(mx);
      float sm = __expf(v0.x - mx) + __expf(v0.y - mx) + __expf(v0.z - mx) +
                 __expf(v0.w - mx) + __expf(v1.x - mx) + __expf(v1.y - mx) +
                 __expf(v1.z - mx) + __expf(v1.w - mx) + __expf(v2.x - mx) +
                 __expf(v2.y - mx) + __expf(v2.z - mx) + __expf(v2.w - mx) +
                 __expf(v3.x - mx) + __expf(v3.y - mx) + __expf(v3.z - mx) +
                 __expf(v3.w - mx);
      sm = wave_sum64(sm);
      const float lse = mx + __logf(sm);
      *(float4*)(rowbuf + 0 * 256 + 4 * lane) = v0;
      *(float4*)(rowbuf + 1 * 256 + 4 * lane) = v1;
      *(float4*)(rowbuf + 2 * 256 + 4 * lane) = v2;
      *(float4*)(rowbuf + 3 * 256 + 4 * lane) = v3;
      const int* tgb = targets + (size_t)b * S;
      const size_t rb = (size_t)b * Tp + t;
      float* gr = gw + rb * 256;
#pragma unroll
      for (int i4 = 0; i4 < 4; ++i4) {
        const int i = lane + 64 * i4;
        const int cls = tgb[i];
        gr[i] = __expf(rowbuf[cls] - lse);
      }
      if (lane == 0) {
        qw[rb] = __expf(rowbuf[0] - lse);
        const int grp = (t == 0) ? 0 : ((t - 1) >> 4);
        __hip_atomic_fetch_add(flags + b * FS + grp, 1, __ATOMIC_RELEASE,
                               __HIP_MEMORY_SCOPE_AGENT);
      }
    }
    return;
  }

  if (threadIdx.x >= 64) return;
  // ---------------- consumer: alpha recursion, 1 wave per batch ----------------
  const int b = blockIdx.x;
  const int len = in_len[b];
  const int tl = tgt_len[b];
  const int* tg = targets + (size_t)b * S;
  const int4 mytg = *(const int4*)(tg + 4 * lane);
  const int tgm1 = (lane > 0) ? tg[4 * lane - 1] : -1;
  const float sk1 = (lane > 0 && mytg.x != tgm1) ? 1.f : 0.f;
  const float sk3 = (mytg.y != mytg.x) ? 1.f : 0.f;
  const float sk5 = (mytg.z != mytg.y) ? 1.f : 0.f;
  const float sk7 = (mytg.w != mytg.z) ? 1.f : 0.f;

  const int N = len - 1;           // steps t = 1..len-1
  const int NTb = (N + 15) >> 4;   // 16-step tiles
  int* fb = flags + b * FS;
  const int Tm1 = T - 1;
  const size_t base = (size_t)b * Tp;

  auto waitflag = [&](int g) {
    const int tgt = ((g == 0) ? 1 : 0) + min(16, Tm1 - 16 * g);
    int it = 0;
    while (__hip_atomic_load(fb + g, __ATOMIC_ACQUIRE,
                             __HIP_MEMORY_SCOPE_AGENT) < tgt) {
      __builtin_amdgcn_s_sleep(1);
      if (++it > (1 << 27)) break;  // bail instead of hang
    }
  };
  auto issue = [&](int j) {
    const int s = j % 3;
    const size_t r0 = base + 1 + 16 * (size_t)j;
    const float* src = gw + r0 * 256 + 4 * lane;
    float* dp = lds + s * 4096;
#pragma unroll
    for (int r = 0; r < 16; ++r) GLL16(src + r * 256, dp + r * 256);
    GLL4(qw + r0 + lane, lds + 12288 + s * 64);
  };

  float a0 = 0.f, a1 = 0.f, a2 = 0.f, a3 = 0.f, a4 = 0.f, a5 = 0.f, a6 = 0.f,
        a7 = 0.f, a8 = 0.f;
  int E = 0;

  waitflag(0);
  if (lane == 0) {
    a0 = qw[base];            // t=0 blank
    a1 = gw[base * 256];      // t=0 first label
  }
  issue(0);
  if (NTb > 1) { waitflag(1); issue(1); }
  if (NTb > 2) { waitflag(2); issue(2); }

#define KS(k)                                                       \
  {                                                                 \
    const float4 pv = *(const float4*)(Pb + (k) * 256 + 4 * lane);  \
    const float pbv = Qb[k];                                        \
    float hm1 = __shfl_up(a7, 1, 64);                               \
    hm1 = (lane == 0) ? 0.f : hm1;                                  \
    const float n0 = (a0 + hm1) * pbv;                              \
    const float n1 = __fmaf_rn(sk1, hm1, a1 + a0) * pv.x;           \
    const float n2 = (a2 + a1) * pbv;                               \
    const float n3 = __fmaf_rn(sk3, a1, a3 + a2) * pv.y;            \
    const float n4 = (a4 + a3) * pbv;                               \
    const float n5 = __fmaf_rn(sk5, a3, a5 + a4) * pv.z;            \
    const float n6 = (a6 + a5) * pbv;                               \
    const float n7 = __fmaf_rn(sk7, a5, a7 + a6) * pv.w;            \
    const float n8 = (a8 + a7) * pbv;                               \
    a0 = n0; a1 = n1; a2 = n2; a3 = n3; a4 = n4;                    \
    a5 = n5; a6 = n6; a7 = n7; a8 = n8;                             \
  }

#define RESC()                                                            \
  {                                                                       \
    float m_ = fmaxf(fmaxf(fmaxf(fmaxf(a0, a1), fmaxf(a2, a3)),           \
                           fmaxf(fmaxf(a4, a5), fmaxf(a6, a7))), a8);     \
    m_ = wave_max_dpp(m_);                                                \
    const int e_ =                                                        \
        (m_ > 0.f) ? (int)((__float_as_uint(m_) >> 23) & 255u) - 127 : 0; \
    a0 = ldexpf(a0, -e_); a1 = ldexpf(a1, -e_); a2 = ldexpf(a2, -e_);     \
    a3 = ldexpf(a3, -e_); a4 = ldexpf(a4, -e_); a5 = ldexpf(a5, -e_);     \
    a6 = ldexpf(a6, -e_); a7 = ldexpf(a7, -e_); a8 = ldexpf(a8, -e_);     \
    E += e_;                                                              \
  }

  for (int j = 0; j < NTb; ++j) {
    const int infl = NTb - j;
    if (infl >= 3) {
      asm volatile("s_waitcnt vmcnt(34)" ::: "memory");
    } else if (infl == 2) {
      asm volatile("s_waitcnt vmcnt(17)" ::: "memory");
    } else {
      asm volatile("s_waitcnt vmcnt(0)" ::: "memory");
    }
    __builtin_amdgcn_sched_barrier(0);
    const int s = j % 3;
    const float* Pb = lds + s * 4096;
    const float* Qb = lds + 12288 + s * 64;
    const int rem = N - 16 * j;
    if (rem >= 16) {
      KS(0) KS(1) KS(2) KS(3) KS(4) KS(5) KS(6) KS(7) RESC()
      KS(8) KS(9) KS(10) KS(11) KS(12) KS(13) KS(14) KS(15) RESC()
    } else if (rem > 0) {
      KS(0)
      if (rem > 1) KS(1)
      if (rem > 2) KS(2)
      if (rem > 3) KS(3)
      if (rem > 4) KS(4)
      if (rem > 5) KS(5)
      if (rem > 6) KS(6)
      if (rem > 7) KS(7)
      RESC()
      if (rem > 8) {
        KS(8)
        if (rem > 9) KS(9)
        if (rem > 10) KS(10)
        if (rem > 11) KS(11)
        if (rem > 12) KS(12)
        if (rem > 13) KS(13)
        if (rem > 14) KS(14)
        RESC()
      }
    }
    if (j + 3 < NTb) {
      waitflag(j + 3);
      issue(j + 3);
    }
  }

  float* fin = lds + 12480;
  fin[8 * lane + 0] = a0; fin[8 * lane + 1] = a1;
  fin[8 * lane + 2] = a2; fin[8 * lane + 3] = a3;
  fin[8 * lane + 4] = a4; fin[8 * lane + 5] = a5;
  fin[8 * lane + 6] = a6; fin[8 * lane + 7] = a7;
  if (lane == 63) fin[512] = a8;
  asm volatile("s_waitcnt lgkmcnt(0)" ::: "memory");
  __builtin_amdgcn_sched_barrier(0);
  if (lane == 0) {
    const int i1 = 2 * tl;
    const int i2 = (2 * tl - 1 > 0) ? (2 * tl - 1) : 0;
    float v = fin[i1] + ((tl > 0) ? fin[i2] : 0.f);
    v = fmaxf(v, 1e-37f);
    tot[b] = logf(v) + (float)E * 0.6931471805599453f;
  }
#undef KS
#undef RESC
}

__global__ void k3_mean(const float* __restrict__ tot, float* __restrict__ out,
                        int B) {
  float v = (threadIdx.x < B) ? tot[threadIdx.x] : 0.0f;
  v = wave_sum64(v);
  if (threadIdx.x == 0) out[0] = -v / (float)B;
}

extern "C" void kernel_launch(void* const* d_in, const int* in_sizes, int n_in,
                              void* d_out, int out_size, void* d_ws,
                              size_t ws_size, hipStream_t stream) {
  const float* lp = (const float*)d_in[0];
  const int* targets = (const int*)d_in[1];
  const int* in_len = (const int*)d_in[2];
  const int* tgt_len = (const int*)d_in[3];
  float* out = (float*)d_out;

  const int B = in_sizes[2];               // 64
  const int S = in_sizes[1] / B;           // 256
  const int C = 1024;
  const int T = (int)((size_t)in_sizes[0] / ((size_t)B * C));  // 2048
  const int Tp = T + 64;                   // padded rows (over-read safety)

  // ws layout (floats): tot[64] | flags[64*FS ints] | q[B*Tp] | gP[B*Tp*256]
  float* tot = (float*)d_ws;
  int* flags = (int*)(tot + 64);
  float* qw = (float*)(flags + 64 * FS);
  float* gw = qw + (size_t)64 * Tp;

  k0_init<<<1, 256, 0, stream>>>(flags, 64 * FS);
  mega<<<64 + NPROD, 256, 0, stream>>>(lp, targets, in_len, tgt_len, gw, qw,
                                       flags, tot, T, S, Tp);
  k3_mean<<<1, 64, 0, stream>>>(tot, out, B);
}

// Round 5
// 349.469 us; speedup vs baseline: 12.6769x; 12.6769x over previous
//
#include <hip/hip_runtime.h>
#include <hip/hip_fp16.h>
#include <math.h>

// global -> LDS async DMA (size literal; LDS dest = wave-uniform base + lane*size)
#define GLL16(gp, lp_)                                                     \
  __builtin_amdgcn_global_load_lds(                                        \
      (const __attribute__((address_space(1))) void*)(gp),                 \
      (__attribute__((address_space(3))) void*)(lp_), 16, 0, 0)
#define GLL4(gp, lp_)                                                      \
  __builtin_amdgcn_global_load_lds(                                        \
      (const __attribute__((address_space(1))) void*)(gp),                 \
      (__attribute__((address_space(3))) void*)(lp_), 4, 0, 0)

__device__ inline float wave_max64(float v) {
#pragma unroll
  for (int off = 32; off > 0; off >>= 1) v = fmaxf(v, __shfl_xor(v, off, 64));
  return v;
}
__device__ inline float wave_sum64(float v) {
#pragma unroll
  for (int off = 32; off > 0; off >>= 1) v += __shfl_xor(v, off, 64);
  return v;
}
// wave64 max via DPP, result broadcast (verified working in round 4)
__device__ inline float wave_max_dpp(float x) {
  int xi = __float_as_int(x);
  x = fmaxf(x, __int_as_float(__builtin_amdgcn_update_dpp(xi, xi, 0x111, 0xf, 0xf, false)));
  xi = __float_as_int(x);
  x = fmaxf(x, __int_as_float(__builtin_amdgcn_update_dpp(xi, xi, 0x112, 0xf, 0xf, false)));
  xi = __float_as_int(x);
  x = fmaxf(x, __int_as_float(__builtin_amdgcn_update_dpp(xi, xi, 0x114, 0xf, 0xf, false)));
  xi = __float_as_int(x);
  x = fmaxf(x, __int_as_float(__builtin_amdgcn_update_dpp(xi, xi, 0x118, 0xf, 0xf, false)));
  xi = __float_as_int(x);
  x = fmaxf(x, __int_as_float(__builtin_amdgcn_update_dpp(xi, xi, 0x142, 0xa, 0xf, false)));
  xi = __float_as_int(x);
  x = fmaxf(x, __int_as_float(__builtin_amdgcn_update_dpp(xi, xi, 0x143, 0xc, 0xf, false)));
  return __int_as_float(__builtin_amdgcn_readlane(__float_as_int(x), 63));
}

// ---------------- K1: log-softmax + gather -> fp16 probs, row-pair packed ----
// Wave w handles chunk-local row pair p: rows t0+2p, t0+2p+1.
// Packed layout: pair-row = 1024 B; lane l's 16 B = {rowEven labels 4l..4l+3 (4 half),
// rowOdd labels 4l..4l+3}. Blank probs go to qw (f32).
__global__ __launch_bounds__(256) void k1_gather(
    const float* __restrict__ lp, const int* __restrict__ targets,
    unsigned short* __restrict__ gw, float* __restrict__ qw,
    int t0, int T, int Tc, int PRB, int Tcp, int S) {
  __shared__ __align__(16) float rowbuf4[4][2][1024];
  const int w = threadIdx.x >> 6;
  const int lane = threadIdx.x & 63;
  const int p = blockIdx.x * 4 + w;
  const int b = blockIdx.y;
  const int4 tg4 = *(const int4*)(targets + (size_t)b * S + 4 * lane);

  unsigned int hp[4];
  float q0 = 0.f, q1 = 0.f;
#pragma unroll
  for (int hf = 0; hf < 2; ++hf) {
    float* rowbuf = rowbuf4[w][hf];
    const int t = t0 + 2 * p + hf;
    const float* row = lp + ((size_t)b * T + t) * 1024;
    const float4 v0 = *(const float4*)(row + 4 * lane);
    const float4 v1 = *(const float4*)(row + 256 + 4 * lane);
    const float4 v2 = *(const float4*)(row + 512 + 4 * lane);
    const float4 v3 = *(const float4*)(row + 768 + 4 * lane);
    float mx = fmaxf(fmaxf(fmaxf(v0.x, v0.y), fmaxf(v0.z, v0.w)),
                     fmaxf(fmaxf(v1.x, v1.y), fmaxf(v1.z, v1.w)));
    mx = fmaxf(mx, fmaxf(fmaxf(fmaxf(v2.x, v2.y), fmaxf(v2.z, v2.w)),
                         fmaxf(fmaxf(v3.x, v3.y), fmaxf(v3.z, v3.w))));
    mx = wave_max64(mx);
    float sm = __expf(v0.x - mx) + __expf(v0.y - mx) + __expf(v0.z - mx) +
               __expf(v0.w - mx) + __expf(v1.x - mx) + __expf(v1.y - mx) +
               __expf(v1.z - mx) + __expf(v1.w - mx) + __expf(v2.x - mx) +
               __expf(v2.y - mx) + __expf(v2.z - mx) + __expf(v2.w - mx) +
               __expf(v3.x - mx) + __expf(v3.y - mx) + __expf(v3.z - mx) +
               __expf(v3.w - mx);
    sm = wave_sum64(sm);
    const float lse = mx + __logf(sm);
    *(float4*)(rowbuf + 4 * lane) = v0;
    *(float4*)(rowbuf + 256 + 4 * lane) = v1;
    *(float4*)(rowbuf + 512 + 4 * lane) = v2;
    *(float4*)(rowbuf + 768 + 4 * lane) = v3;
    // same-wave LDS ops complete in order; compiler keeps order via aliasing
    const float e0 = __expf(rowbuf[tg4.x] - lse);
    const float e1 = __expf(rowbuf[tg4.y] - lse);
    const float e2 = __expf(rowbuf[tg4.z] - lse);
    const float e3 = __expf(rowbuf[tg4.w] - lse);
    const unsigned s0 = __half_as_ushort(__float2half(e0));
    const unsigned s1 = __half_as_ushort(__float2half(e1));
    const unsigned s2 = __half_as_ushort(__float2half(e2));
    const unsigned s3 = __half_as_ushort(__float2half(e3));
    hp[2 * hf + 0] = s0 | (s1 << 16);
    hp[2 * hf + 1] = s2 | (s3 << 16);
    const float qv = __expf(rowbuf[0] - lse);
    if (hf == 0) q0 = qv; else q1 = qv;
  }
  *(uint4*)((char*)gw + ((size_t)b * PRB + p) * 1024 + 16 * lane) =
      make_uint4(hp[0], hp[1], hp[2], hp[3]);
  if (lane == 0) {
    float* qp = qw + (size_t)b * Tcp + 2 * p;  // chunk-local row index
    qp[0] = q0; qp[1] = q1;
  }
}

// ---------------- K2: alpha recursion, 1 wave/batch, LDS-DMA pipeline --------
// TSREL = 1 for the first chunk (steps start at t=1), else 0.
// LDS floats: P ring 3*2304 (9 pair-rows/tile) | Q ring @6912 3*64 | fin @7104 513
template <int TSREL>
__global__ __launch_bounds__(64, 1) void k2_alpha(
    const unsigned short* __restrict__ gw, const float* __restrict__ qw,
    const int* __restrict__ targets, const int* __restrict__ in_len,
    const int* __restrict__ tgt_len, float* __restrict__ alpha_g,
    int* __restrict__ exp_g, float* __restrict__ tot,
    int t0, int Tc, int PRB, int Tcp, int S, int is_last) {
  __shared__ float lds[7620];
  const int b = blockIdx.x;
  const int lane = threadIdx.x;
  const char* gb = (const char*)gw + (size_t)b * PRB * 1024;
  const float* qb = qw + (size_t)b * Tcp;
  const int len = in_len[b];
  const int tl = tgt_len[b];
  const int* tg = targets + (size_t)b * S;
  const int4 mytg = *(const int4*)(tg + 4 * lane);
  const int tgm1 = (lane > 0) ? tg[4 * lane - 1] : -1;
  const float sk1 = (lane > 0 && mytg.x != tgm1) ? 1.f : 0.f;
  const float sk3 = (mytg.y != mytg.x) ? 1.f : 0.f;
  const float sk5 = (mytg.z != mytg.y) ? 1.f : 0.f;
  const float sk7 = (mytg.w != mytg.z) ? 1.f : 0.f;

  float a0 = 0.f, a1 = 0.f, a2 = 0.f, a3 = 0.f, a4 = 0.f, a5 = 0.f, a6 = 0.f,
        a7 = 0.f, a8 = 0.f;
  int E = 0;
  if (TSREL) {
    if (lane == 0) {
      a0 = qb[0];  // t=0 blank
      a1 = __half2float(__ushort_as_half(((const unsigned short*)gb)[0]));
    }
  } else {
    const float* ap = alpha_g + (size_t)b * 520 + 8 * lane;
    a0 = ap[0]; a1 = ap[1]; a2 = ap[2]; a3 = ap[3];
    a4 = ap[4]; a5 = ap[5]; a6 = ap[6]; a7 = ap[7];
    a8 = (lane == 63) ? alpha_g[(size_t)b * 520 + 512] : 0.f;
    E = exp_g[b];
  }

  const int t_hi = min(t0 + Tc, len);
  int N = t_hi - (t0 + TSREL);
  if (N < 0) N = 0;
  const int NTb = (N + 15) >> 4;
  char* ldsb = (char*)lds;

  auto issue = [&](int j) {
    const int s = j - (j / 3) * 3;
    const int p0 = (TSREL + 16 * j) >> 1;
    const char* src = gb + (size_t)p0 * 1024 + 16 * lane;
    float* dp = lds + s * 2304;
#pragma unroll
    for (int r = 0; r < 9; ++r) GLL16(src + r * 1024, dp + r * 256);
    GLL4(qb + (TSREL + 16 * j) + lane, lds + 6912 + s * 64);
  };

  if (NTb > 0) issue(0);
  if (NTb > 1) issue(1);
  if (NTb > 2) issue(2);

#define KS(k)                                                                  \
  {                                                                            \
    const uint2 du = *(const uint2*)(Pb + ((((k) + TSREL) >> 1) * 1024 +       \
                                           (((k) + TSREL) & 1) * 8));          \
    const float pbv = Qb[k];                                                   \
    const float px = __half2float(__ushort_as_half((unsigned short)(du.x & 0xffffu))); \
    const float py = __half2float(__ushort_as_half((unsigned short)(du.x >> 16)));     \
    const float pz = __half2float(__ushort_as_half((unsigned short)(du.y & 0xffffu))); \
    const float pw = __half2float(__ushort_as_half((unsigned short)(du.y >> 16)));     \
    float hm1 = __shfl_up(a7, 1, 64);                                          \
    hm1 = (lane == 0) ? 0.f : hm1;                                             \
    const float n0 = (a0 + hm1) * pbv;                                         \
    const float n1 = __fmaf_rn(sk1, hm1, a1 + a0) * px;                        \
    const float n2 = (a2 + a1) * pbv;                                          \
    const float n3 = __fmaf_rn(sk3, a1, a3 + a2) * py;                         \
    const float n4 = (a4 + a3) * pbv;                                          \
    const float n5 = __fmaf_rn(sk5, a3, a5 + a4) * pz;                         \
    const float n6 = (a6 + a5) * pbv;                                          \
    const float n7 = __fmaf_rn(sk7, a5, a7 + a6) * pw;                         \
    const float n8 = (a8 + a7) * pbv;                                          \
    a0 = n0; a1 = n1; a2 = n2; a3 = n3; a4 = n4;                               \
    a5 = n5; a6 = n6; a7 = n7; a8 = n8;                                        \
  }

#define RESC()                                                            \
  {                                                                       \
    float m_ = fmaxf(fmaxf(fmaxf(fmaxf(a0, a1), fmaxf(a2, a3)),           \
                           fmaxf(fmaxf(a4, a5), fmaxf(a6, a7))), a8);     \
    m_ = wave_max_dpp(m_);                                                \
    const int e_ =                                                        \
        (m_ > 0.f) ? (int)((__float_as_uint(m_) >> 23) & 255u) - 127 : 0; \
    a0 = ldexpf(a0, -e_); a1 = ldexpf(a1, -e_); a2 = ldexpf(a2, -e_);     \
    a3 = ldexpf(a3, -e_); a4 = ldexpf(a4, -e_); a5 = ldexpf(a5, -e_);     \
    a6 = ldexpf(a6, -e_); a7 = ldexpf(a7, -e_); a8 = ldexpf(a8, -e_);     \
    E += e_;                                                              \
  }

  for (int j = 0; j < NTb; ++j) {
    const int infl = NTb - j;
    if (infl >= 3) {
      asm volatile("s_waitcnt vmcnt(20)" ::: "memory");
    } else if (infl == 2) {
      asm volatile("s_waitcnt vmcnt(10)" ::: "memory");
    } else {
      asm volatile("s_waitcnt vmcnt(0)" ::: "memory");
    }
    __builtin_amdgcn_sched_barrier(0);
    const int s = j - (j / 3) * 3;
    const char* Pb = ldsb + s * 9216 + 16 * lane;
    const float* Qb = lds + 6912 + s * 64;
    const int rem = N - 16 * j;
    if (rem >= 16) {
      KS(0) KS(1) KS(2) KS(3) KS(4) KS(5) KS(6) KS(7) RESC()
      KS(8) KS(9) KS(10) KS(11) KS(12) KS(13) KS(14) KS(15) RESC()
    } else {
      KS(0)
      if (rem > 1) KS(1)
      if (rem > 2) KS(2)
      if (rem > 3) KS(3)
      if (rem > 4) KS(4)
      if (rem > 5) KS(5)
      if (rem > 6) KS(6)
      if (rem > 7) KS(7)
      RESC()
      if (rem > 8) {
        KS(8)
        if (rem > 9) KS(9)
        if (rem > 10) KS(10)
        if (rem > 11) KS(11)
        if (rem > 12) KS(12)
        if (rem > 13) KS(13)
        if (rem > 14) KS(14)
        RESC()
      }
    }
    if (j + 3 < NTb) issue(j + 3);
  }
#undef KS
#undef RESC

  if (is_last) {
    float* fin = lds + 7104;
    fin[8 * lane + 0] = a0; fin[8 * lane + 1] = a1;
    fin[8 * lane + 2] = a2; fin[8 * lane + 3] = a3;
    fin[8 * lane + 4] = a4; fin[8 * lane + 5] = a5;
    fin[8 * lane + 6] = a6; fin[8 * lane + 7] = a7;
    if (lane == 63) fin[512] = a8;
    asm volatile("s_waitcnt lgkmcnt(0)" ::: "memory");
    __builtin_amdgcn_sched_barrier(0);
    if (lane == 0) {
      const int i1 = 2 * tl;
      const int i2 = (2 * tl - 1 > 0) ? (2 * tl - 1) : 0;
      float v = fin[i1] + ((tl > 0) ? fin[i2] : 0.f);
      v = fmaxf(v, 1e-37f);
      tot[b] = logf(v) + (float)E * 0.6931471805599453f;
    }
  } else {
    float* ap = alpha_g + (size_t)b * 520 + 8 * lane;
    ap[0] = a0; ap[1] = a1; ap[2] = a2; ap[3] = a3;
    ap[4] = a4; ap[5] = a5; ap[6] = a6; ap[7] = a7;
    if (lane == 63) alpha_g[(size_t)b * 520 + 512] = a8;
    if (lane == 0) exp_g[b] = E;
  }
}

// ---------------- K3: -mean over batch ----------------
__global__ void k3_mean(const float* __restrict__ tot, float* __restrict__ out,
                        int B) {
  float v = (threadIdx.x < B) ? tot[threadIdx.x] : 0.0f;
  v = wave_sum64(v);
  if (threadIdx.x == 0) out[0] = -v / (float)B;
}

// ---------------- host ----------------
extern "C" void kernel_launch(void* const* d_in, const int* in_sizes, int n_in,
                              void* d_out, int out_size, void* d_ws,
                              size_t ws_size, hipStream_t stream) {
  const float* lp = (const float*)d_in[0];
  const int* targets = (const int*)d_in[1];
  const int* in_len = (const int*)d_in[2];
  const int* tgt_len = (const int*)d_in[3];
  float* out = (float*)d_out;

  const int B = in_sizes[2];               // 64
  const int S = in_sizes[1] / B;           // 256
  const int C = 1024;
  const int T = (int)((size_t)in_sizes[0] / ((size_t)B * C));  // 2048

  // pick chunk size Tc that fits the workspace
  const size_t headf = 64 + 64 + (size_t)64 * 520;  // tot | exp_g | alpha_g
  int Tc = T, PRB = 0, Tcp = 0;
  for (;;) {
    PRB = Tc / 2 + 8;    // pair-rows per batch (+pad for tile over-read)
    Tcp = Tc + 64;       // qw rows per batch (+pad)
    const size_t need =
        headf * 4 + (size_t)64 * Tcp * 4 + (size_t)64 * PRB * 1024;
    if (need <= ws_size || Tc <= 64) break;
    Tc >>= 1;
  }

  float* tot = (float*)d_ws;
  int* exp_g = (int*)(tot + 64);
  float* alpha_g = (float*)(exp_g + 64);
  float* qw = alpha_g + (size_t)64 * 520;
  unsigned short* gw = (unsigned short*)(qw + (size_t)64 * Tcp);

  const int nch = (T + Tc - 1) / Tc;
  for (int c = 0; c < nch; ++c) {
    const int t0 = c * Tc;
    k1_gather<<<dim3(Tc / 8, B), 256, 0, stream>>>(lp, targets, gw, qw, t0, T,
                                                   Tc, PRB, Tcp, S);
    const int last = (c == nch - 1) ? 1 : 0;
    if (c == 0)
      k2_alpha<1><<<B, 64, 0, stream>>>(gw, qw, targets, in_len, tgt_len,
                                        alpha_g, exp_g, tot, t0, Tc, PRB, Tcp,
                                        S, last);
    else
      k2_alpha<0><<<B, 64, 0, stream>>>(gw, qw, targets, in_len, tgt_len,
                                        alpha_g, exp_g, tot, t0, Tc, PRB, Tcp,
                                        S, last);
  }
  k3_mean<<<1, 64, 0, stream>>>(tot, out, B);
}

// Round 6
// 333.074 us; speedup vs baseline: 13.3008x; 1.0492x over previous
//
#include <hip/hip_runtime.h>
#include <hip/hip_fp16.h>
#include <math.h>

// global -> LDS async DMA (size literal; LDS dest = wave-uniform base + lane*size)
#define GLL16(gp, lp_)                                                     \
  __builtin_amdgcn_global_load_lds(                                        \
      (const __attribute__((address_space(1))) void*)(gp),                 \
      (__attribute__((address_space(3))) void*)(lp_), 16, 0, 0)
#define GLL4(gp, lp_)                                                      \
  __builtin_amdgcn_global_load_lds(                                        \
      (const __attribute__((address_space(1))) void*)(gp),                 \
      (__attribute__((address_space(3))) void*)(lp_), 4, 0, 0)

__device__ inline float wave_max64(float v) {
#pragma unroll
  for (int off = 32; off > 0; off >>= 1) v = fmaxf(v, __shfl_xor(v, off, 64));
  return v;
}
__device__ inline float wave_sum64(float v) {
#pragma unroll
  for (int off = 32; off > 0; off >>= 1) v += __shfl_xor(v, off, 64);
  return v;
}
// wave64 max via DPP, result broadcast (verified working rounds 4-5)
__device__ inline float wave_max_dpp(float x) {
  int xi = __float_as_int(x);
  x = fmaxf(x, __int_as_float(__builtin_amdgcn_update_dpp(xi, xi, 0x111, 0xf, 0xf, false)));
  xi = __float_as_int(x);
  x = fmaxf(x, __int_as_float(__builtin_amdgcn_update_dpp(xi, xi, 0x112, 0xf, 0xf, false)));
  xi = __float_as_int(x);
  x = fmaxf(x, __int_as_float(__builtin_amdgcn_update_dpp(xi, xi, 0x114, 0xf, 0xf, false)));
  xi = __float_as_int(x);
  x = fmaxf(x, __int_as_float(__builtin_amdgcn_update_dpp(xi, xi, 0x118, 0xf, 0xf, false)));
  xi = __float_as_int(x);
  x = fmaxf(x, __int_as_float(__builtin_amdgcn_update_dpp(xi, xi, 0x142, 0xa, 0xf, false)));
  xi = __float_as_int(x);
  x = fmaxf(x, __int_as_float(__builtin_amdgcn_update_dpp(xi, xi, 0x143, 0xc, 0xf, false)));
  return __int_as_float(__builtin_amdgcn_readlane(__float_as_int(x), 63));
}
// lane l <- x from lane l-1; lane 0 <- 0. Single VALU DPP (wave_shr:1), no LDS pipe.
__device__ inline float lane_shr1(float x) {
  return __int_as_float(__builtin_amdgcn_update_dpp(
      0, __float_as_int(x), 0x138 /*WAVE_SHR1*/, 0xf, 0xf, true /*bound_ctrl: invalid->0*/));
}

// ---------------- K1: log-softmax + gather -> fp16 probs, row-pair packed ----
__global__ __launch_bounds__(256) void k1_gather(
    const float* __restrict__ lp, const int* __restrict__ targets,
    unsigned short* __restrict__ gw, float* __restrict__ qw,
    int t0, int T, int Tc, int PRB, int Tcp, int S) {
  __shared__ __align__(16) float rowbuf4[4][2][1024];
  const int w = threadIdx.x >> 6;
  const int lane = threadIdx.x & 63;
  const int p = blockIdx.x * 4 + w;
  const int b = blockIdx.y;
  const int4 tg4 = *(const int4*)(targets + (size_t)b * S + 4 * lane);

  unsigned int hp[4];
  float q0 = 0.f, q1 = 0.f;
#pragma unroll
  for (int hf = 0; hf < 2; ++hf) {
    float* rowbuf = rowbuf4[w][hf];
    const int t = t0 + 2 * p + hf;
    const float* row = lp + ((size_t)b * T + t) * 1024;
    const float4 v0 = *(const float4*)(row + 4 * lane);
    const float4 v1 = *(const float4*)(row + 256 + 4 * lane);
    const float4 v2 = *(const float4*)(row + 512 + 4 * lane);
    const float4 v3 = *(const float4*)(row + 768 + 4 * lane);
    float mx = fmaxf(fmaxf(fmaxf(v0.x, v0.y), fmaxf(v0.z, v0.w)),
                     fmaxf(fmaxf(v1.x, v1.y), fmaxf(v1.z, v1.w)));
    mx = fmaxf(mx, fmaxf(fmaxf(fmaxf(v2.x, v2.y), fmaxf(v2.z, v2.w)),
                         fmaxf(fmaxf(v3.x, v3.y), fmaxf(v3.z, v3.w))));
    mx = wave_max64(mx);
    float sm = __expf(v0.x - mx) + __expf(v0.y - mx) + __expf(v0.z - mx) +
               __expf(v0.w - mx) + __expf(v1.x - mx) + __expf(v1.y - mx) +
               __expf(v1.z - mx) + __expf(v1.w - mx) + __expf(v2.x - mx) +
               __expf(v2.y - mx) + __expf(v2.z - mx) + __expf(v2.w - mx) +
               __expf(v3.x - mx) + __expf(v3.y - mx) + __expf(v3.z - mx) +
               __expf(v3.w - mx);
    sm = wave_sum64(sm);
    const float lse = mx + __logf(sm);
    *(float4*)(rowbuf + 4 * lane) = v0;
    *(float4*)(rowbuf + 256 + 4 * lane) = v1;
    *(float4*)(rowbuf + 512 + 4 * lane) = v2;
    *(float4*)(rowbuf + 768 + 4 * lane) = v3;
    const float e0 = __expf(rowbuf[tg4.x] - lse);
    const float e1 = __expf(rowbuf[tg4.y] - lse);
    const float e2 = __expf(rowbuf[tg4.z] - lse);
    const float e3 = __expf(rowbuf[tg4.w] - lse);
    const unsigned s0 = __half_as_ushort(__float2half(e0));
    const unsigned s1 = __half_as_ushort(__float2half(e1));
    const unsigned s2 = __half_as_ushort(__float2half(e2));
    const unsigned s3 = __half_as_ushort(__float2half(e3));
    hp[2 * hf + 0] = s0 | (s1 << 16);
    hp[2 * hf + 1] = s2 | (s3 << 16);
    const float qv = __expf(rowbuf[0] - lse);
    if (hf == 0) q0 = qv; else q1 = qv;
  }
  *(uint4*)((char*)gw + ((size_t)b * PRB + p) * 1024 + 16 * lane) =
      make_uint4(hp[0], hp[1], hp[2], hp[3]);
  if (lane == 0) {
    float* qp = qw + (size_t)b * Tcp + 2 * p;
    qp[0] = q0; qp[1] = q1;
  }
}

// ---------------- K2: alpha recursion, 1 wave/batch, LDS-DMA pipeline --------
// LDS floats: P ring 3*2304 (9 pair-rows/tile) | Q ring @6912 3*64 | fin @7104 513
template <int TSREL>
__global__ __launch_bounds__(64, 1) void k2_alpha(
    const unsigned short* __restrict__ gw, const float* __restrict__ qw,
    const int* __restrict__ targets, const int* __restrict__ in_len,
    const int* __restrict__ tgt_len, float* __restrict__ alpha_g,
    int* __restrict__ exp_g, float* __restrict__ tot,
    int t0, int Tc, int PRB, int Tcp, int S, int is_last) {
  __shared__ float lds[7620];
  const int b = blockIdx.x;
  const int lane = threadIdx.x;
  const char* gb = (const char*)gw + (size_t)b * PRB * 1024;
  const float* qb = qw + (size_t)b * Tcp;
  const int len = in_len[b];
  const int tl = tgt_len[b];
  const int* tg = targets + (size_t)b * S;
  const int4 mytg = *(const int4*)(tg + 4 * lane);
  const int tgm1 = (lane > 0) ? tg[4 * lane - 1] : -1;
  const float sk1 = (lane > 0 && mytg.x != tgm1) ? 1.f : 0.f;
  const float sk3 = (mytg.y != mytg.x) ? 1.f : 0.f;
  const float sk5 = (mytg.z != mytg.y) ? 1.f : 0.f;
  const float sk7 = (mytg.w != mytg.z) ? 1.f : 0.f;

  float a0 = 0.f, a1 = 0.f, a2 = 0.f, a3 = 0.f, a4 = 0.f, a5 = 0.f, a6 = 0.f,
        a7 = 0.f, a8 = 0.f;
  int E = 0;
  if (TSREL) {
    if (lane == 0) {
      a0 = qb[0];  // t=0 blank
      a1 = __half2float(__ushort_as_half(((const unsigned short*)gb)[0]));
    }
  } else {
    const float* ap = alpha_g + (size_t)b * 520 + 8 * lane;
    a0 = ap[0]; a1 = ap[1]; a2 = ap[2]; a3 = ap[3];
    a4 = ap[4]; a5 = ap[5]; a6 = ap[6]; a7 = ap[7];
    a8 = (lane == 63) ? alpha_g[(size_t)b * 520 + 512] : 0.f;
    E = exp_g[b];
  }

  const int t_hi = min(t0 + Tc, len);
  int N = t_hi - (t0 + TSREL);
  if (N < 0) N = 0;
  const int NTb = (N + 15) >> 4;
  char* ldsb = (char*)lds;

  auto issue = [&](int j) {
    const int s = j - (j / 3) * 3;
    const int p0 = (TSREL + 16 * j) >> 1;
    const char* src = gb + (size_t)p0 * 1024 + 16 * lane;
    float* dp = lds + s * 2304;
#pragma unroll
    for (int r = 0; r < 9; ++r) GLL16(src + r * 1024, dp + r * 256);
    GLL4(qb + (TSREL + 16 * j) + lane, lds + 6912 + s * 64);
  };

  if (NTb > 0) issue(0);
  if (NTb > 1) issue(1);
  if (NTb > 2) issue(2);

#define KS(k)                                                                  \
  {                                                                            \
    const uint2 du = *(const uint2*)(Pb + ((((k) + TSREL) >> 1) * 1024 +       \
                                           (((k) + TSREL) & 1) * 8));          \
    const float pbv = Qb[k];                                                   \
    const float px = __half2float(__ushort_as_half((unsigned short)(du.x & 0xffffu))); \
    const float py = __half2float(__ushort_as_half((unsigned short)(du.x >> 16)));     \
    const float pz = __half2float(__ushort_as_half((unsigned short)(du.y & 0xffffu))); \
    const float pw = __half2float(__ushort_as_half((unsigned short)(du.y >> 16)));     \
    const float hm1 = lane_shr1(a7);                                           \
    const float n0 = (a0 + hm1) * pbv;                                         \
    const float n1 = __fmaf_rn(sk1, hm1, a1 + a0) * px;                        \
    const float n2 = (a2 + a1) * pbv;                                          \
    const float n3 = __fmaf_rn(sk3, a1, a3 + a2) * py;                         \
    const float n4 = (a4 + a3) * pbv;                                          \
    const float n5 = __fmaf_rn(sk5, a3, a5 + a4) * pz;                         \
    const float n6 = (a6 + a5) * pbv;                                          \
    const float n7 = __fmaf_rn(sk7, a5, a7 + a6) * pw;                         \
    const float n8 = (a8 + a7) * pbv;                                          \
    a0 = n0; a1 = n1; a2 = n2; a3 = n3; a4 = n4;                               \
    a5 = n5; a6 = n6; a7 = n7; a8 = n8;                                        \
  }

#define RESC()                                                            \
  {                                                                       \
    float m_ = fmaxf(fmaxf(fmaxf(fmaxf(a0, a1), fmaxf(a2, a3)),           \
                           fmaxf(fmaxf(a4, a5), fmaxf(a6, a7))), a8);     \
    m_ = wave_max_dpp(m_);                                                \
    const int e_ =                                                        \
        (m_ > 0.f) ? (int)((__float_as_uint(m_) >> 23) & 255u) - 127 : 0; \
    a0 = ldexpf(a0, -e_); a1 = ldexpf(a1, -e_); a2 = ldexpf(a2, -e_);     \
    a3 = ldexpf(a3, -e_); a4 = ldexpf(a4, -e_); a5 = ldexpf(a5, -e_);     \
    a6 = ldexpf(a6, -e_); a7 = ldexpf(a7, -e_); a8 = ldexpf(a8, -e_);     \
    E += e_;                                                              \
  }

  for (int j = 0; j < NTb; ++j) {
    const int infl = NTb - j;
    if (infl >= 3) {
      asm volatile("s_waitcnt vmcnt(20)" ::: "memory");
    } else if (infl == 2) {
      asm volatile("s_waitcnt vmcnt(10)" ::: "memory");
    } else {
      asm volatile("s_waitcnt vmcnt(0)" ::: "memory");
    }
    __builtin_amdgcn_sched_barrier(0);
    const int s = j - (j / 3) * 3;
    const char* Pb = ldsb + s * 9216 + 16 * lane;
    const float* Qb = lds + 6912 + s * 64;
    const int rem = N - 16 * j;
    if (rem >= 16) {
      KS(0) KS(1) KS(2) KS(3) KS(4) KS(5) KS(6) KS(7) RESC()
      KS(8) KS(9) KS(10) KS(11) KS(12) KS(13) KS(14) KS(15) RESC()
    } else {
      KS(0)
      if (rem > 1) KS(1)
      if (rem > 2) KS(2)
      if (rem > 3) KS(3)
      if (rem > 4) KS(4)
      if (rem > 5) KS(5)
      if (rem > 6) KS(6)
      if (rem > 7) KS(7)
      RESC()
      if (rem > 8) {
        KS(8)
        if (rem > 9) KS(9)
        if (rem > 10) KS(10)
        if (rem > 11) KS(11)
        if (rem > 12) KS(12)
        if (rem > 13) KS(13)
        if (rem > 14) KS(14)
        RESC()
      }
    }
    if (j + 3 < NTb) issue(j + 3);
  }
#undef KS
#undef RESC

  if (is_last) {
    float* fin = lds + 7104;
    fin[8 * lane + 0] = a0; fin[8 * lane + 1] = a1;
    fin[8 * lane + 2] = a2; fin[8 * lane + 3] = a3;
    fin[8 * lane + 4] = a4; fin[8 * lane + 5] = a5;
    fin[8 * lane + 6] = a6; fin[8 * lane + 7] = a7;
    if (lane == 63) fin[512] = a8;
    asm volatile("s_waitcnt lgkmcnt(0)" ::: "memory");
    __builtin_amdgcn_sched_barrier(0);
    if (lane == 0) {
      const int i1 = 2 * tl;
      const int i2 = (2 * tl - 1 > 0) ? (2 * tl - 1) : 0;
      float v = fin[i1] + ((tl > 0) ? fin[i2] : 0.f);
      v = fmaxf(v, 1e-37f);
      tot[b] = logf(v) + (float)E * 0.6931471805599453f;
    }
  } else {
    float* ap = alpha_g + (size_t)b * 520 + 8 * lane;
    ap[0] = a0; ap[1] = a1; ap[2] = a2; ap[3] = a3;
    ap[4] = a4; ap[5] = a5; ap[6] = a6; ap[7] = a7;
    if (lane == 63) alpha_g[(size_t)b * 520 + 512] = a8;
    if (lane == 0) exp_g[b] = E;
  }
}

// ---------------- K3: -mean over batch ----------------
__global__ void k3_mean(const float* __restrict__ tot, float* __restrict__ out,
                        int B) {
  float v = (threadIdx.x < B) ? tot[threadIdx.x] : 0.0f;
  v = wave_sum64(v);
  if (threadIdx.x == 0) out[0] = -v / (float)B;
}

// ---------------- host ----------------
extern "C" void kernel_launch(void* const* d_in, const int* in_sizes, int n_in,
                              void* d_out, int out_size, void* d_ws,
                              size_t ws_size, hipStream_t stream) {
  const float* lp = (const float*)d_in[0];
  const int* targets = (const int*)d_in[1];
  const int* in_len = (const int*)d_in[2];
  const int* tgt_len = (const int*)d_in[3];
  float* out = (float*)d_out;

  const int B = in_sizes[2];               // 64
  const int S = in_sizes[1] / B;           // 256
  const int C = 1024;
  const int T = (int)((size_t)in_sizes[0] / ((size_t)B * C));  // 2048

  const size_t headf = 64 + 64 + (size_t)64 * 520;  // tot | exp_g | alpha_g
  int Tc = T, PRB = 0, Tcp = 0;
  for (;;) {
    PRB = Tc / 2 + 8;
    Tcp = Tc + 64;
    const size_t need =
        headf * 4 + (size_t)64 * Tcp * 4 + (size_t)64 * PRB * 1024;
    if (need <= ws_size || Tc <= 64) break;
    Tc >>= 1;
  }

  float* tot = (float*)d_ws;
  int* exp_g = (int*)(tot + 64);
  float* alpha_g = (float*)(exp_g + 64);
  float* qw = alpha_g + (size_t)64 * 520;
  unsigned short* gw = (unsigned short*)(qw + (size_t)64 * Tcp);

  const int nch = (T + Tc - 1) / Tc;
  for (int c = 0; c < nch; ++c) {
    const int t0 = c * Tc;
    k1_gather<<<dim3(Tc / 8, B), 256, 0, stream>>>(lp, targets, gw, qw, t0, T,
                                                   Tc, PRB, Tcp, S);
    const int last = (c == nch - 1) ? 1 : 0;
    if (c == 0)
      k2_alpha<1><<<B, 64, 0, stream>>>(gw, qw, targets, in_len, tgt_len,
                                        alpha_g, exp_g, tot, t0, Tc, PRB, Tcp,
                                        S, last);
    else
      k2_alpha<0><<<B, 64, 0, stream>>>(gw, qw, targets, in_len, tgt_len,
                                        alpha_g, exp_g, tot, t0, Tc, PRB, Tcp,
                                        S, last);
  }
  k3_mean<<<1, 64, 0, stream>>>(tot, out, B);
}